// Round 2
// baseline (12174.446 us; speedup 1.0000x reference)
//
#include <hip/hip_runtime.h>
#include <hip/hip_bf16.h>
#include <stdint.h>

#define NF 165
#define NH 128
#define NCOLS 384
#define KT 15
#define NKT 11

__device__ __forceinline__ void atomAddF(float* p, float v) {
    __hip_atomic_fetch_add(p, v, __ATOMIC_RELAXED, __HIP_MEMORY_SCOPE_AGENT);
}

// Count degree(row) via float atomics. edge row array is int32 (harness converts).
__global__ __launch_bounds__(256) void k_deg(
        const int* __restrict__ erow, float* __restrict__ deg, int E) {
    int e = blockIdx.x * 256 + threadIdx.x;
    if (e >= E) return;
    atomAddF(&deg[erow[e]], 1.0f);
}

// deg -> dis = deg>0 ? rsqrt(deg) : 0   (in place)
__global__ __launch_bounds__(256) void k_dis(float* __restrict__ deg, int N) {
    int i = blockIdx.x * 256 + threadIdx.x;
    if (i >= N) return;
    float d = deg[i];
    deg[i] = (d > 0.0f) ? rsqrtf(d) : 0.0f;
}

// norm[e] = -dis[row]*dis[col]
__global__ __launch_bounds__(256) void k_norm(
        const int* __restrict__ erow, const int* __restrict__ ecol,
        const float* __restrict__ dis, float* __restrict__ nrm, int E) {
    int e = blockIdx.x * 256 + threadIdx.x;
    if (e >= E) return;
    nrm[e] = -dis[erow[e]] * dis[ecol[e]];
}

// Build Wc1[165][384]: cols 0..127 = W1[0]-W1[2]; 128..255 = W1[1]; 256..383 = W1[2]
__global__ __launch_bounds__(256) void k_wc1(const float* __restrict__ W1,
                                             float* __restrict__ Wc1) {
    int gid = blockIdx.x * 256 + threadIdx.x;
    if (gid >= NF * NCOLS) return;
    int i = gid / NCOLS;
    int j = gid % NCOLS;
    float v;
    if (j < 128)      v = W1[i * 128 + j] - W1[2 * 21120 + i * 128 + j];
    else if (j < 256) v = W1[21120 + i * 128 + (j - 128)];
    else              v = W1[42240 + i * 128 + (j - 256)];
    Wc1[gid] = v;
}

// Build Wc2[128][8]: cols 0,1 = W2[0]-W2[2]; 2,3 = W2[1]; 4,5 = W2[2]; 6,7 = 0
__global__ __launch_bounds__(256) void k_wc2(const float* __restrict__ W2,
                                             float* __restrict__ Wc2) {
    int gid = blockIdx.x * 256 + threadIdx.x;
    if (gid >= 128 * 8) return;
    int k = gid >> 3;
    int c = gid & 7;
    float v = 0.0f;
    if (c < 2)      v = W2[k * 2 + c] - W2[512 + k * 2 + c];
    else if (c < 4) v = W2[256 + k * 2 + (c - 2)];
    else if (c < 6) v = W2[512 + k * 2 + (c - 4)];
    Wc2[gid] = v;
}

// GEMM1: x[N,165] @ Wc1[165,384] -> u (cols 0..127), s (128..255), w (256..383)
// 64x64 tile per block, 16x16 threads, 4x4 per thread, K-tiles of 15 (11 exact).
__global__ __launch_bounds__(256) void k_gemm1(
        const float* __restrict__ x, const float* __restrict__ Wc,
        float* __restrict__ u, float* __restrict__ s, float* __restrict__ w, int N) {
    __shared__ float As[KT][64];
    __shared__ float Bs[KT][64];

    int row0 = blockIdx.x * 64;
    int col0 = blockIdx.y * 64;   // 0,64,...,320
    int tid = threadIdx.x;
    int tx = tid & 15, ty = tid >> 4;

    float acc[4][4] = {};

    for (int kt = 0; kt < NKT; ++kt) {
        int k0 = kt * KT;
        for (int idx = tid; idx < 64 * KT; idx += 256) {
            int r = idx & 63;
            int k = idx >> 6;
            int row = row0 + r;
            As[k][r] = (row < N) ? x[(size_t)row * NF + k0 + k] : 0.0f;
        }
        for (int idx = tid; idx < KT * 64; idx += 256) {
            int k = idx >> 6;
            int c = idx & 63;
            Bs[k][c] = Wc[(size_t)(k0 + k) * NCOLS + col0 + c];
        }
        __syncthreads();
#pragma unroll
        for (int kk = 0; kk < KT; ++kk) {
            float4 a = *(const float4*)&As[kk][ty * 4];
            float4 b = *(const float4*)&Bs[kk][tx * 4];
            float av[4] = {a.x, a.y, a.z, a.w};
            float bv[4] = {b.x, b.y, b.z, b.w};
#pragma unroll
            for (int i = 0; i < 4; ++i)
#pragma unroll
                for (int j = 0; j < 4; ++j)
                    acc[i][j] += av[i] * bv[j];
        }
        __syncthreads();
    }

    int cbase = col0 + tx * 4;         // tile stays within one 128-col group
    int g = cbase >> 7;
    int cc = cbase & 127;
    float* dst = (g == 0) ? u : (g == 1) ? s : w;
#pragma unroll
    for (int i = 0; i < 4; ++i) {
        int row = row0 + ty * 4 + i;
        if (row < N) {
            float4 v = {acc[i][0], acc[i][1], acc[i][2], acc[i][3]};
            *(float4*)(dst + (size_t)row * NH + cc) = v;
        }
    }
}

// prop on 128-wide features: dst[row] += scale*norm[e]*src[col], 32 threads/edge (float4 each)
__global__ __launch_bounds__(256) void k_prop128(
        const int* __restrict__ erow, const int* __restrict__ ecol,
        const float* __restrict__ nrm, const float* __restrict__ src,
        float* __restrict__ dst, float scale, int E) {
    int gid = blockIdx.x * 256 + threadIdx.x;
    int e = gid >> 5;
    if (e >= E) return;
    int lane = gid & 31;
    int r = erow[e];
    int c = ecol[e];
    float nv = nrm[e] * scale;
    float4 v = *(const float4*)(src + (size_t)c * NH + lane * 4);
    float* d = dst + (size_t)r * NH + lane * 4;
    atomAddF(d + 0, nv * v.x);
    atomAddF(d + 1, nv * v.y);
    atomAddF(d + 2, nv * v.z);
    atomAddF(d + 3, nv * v.w);
}

// h = relu(u + b1) (float4-vectorized)
__global__ __launch_bounds__(256) void k_relu_bias(
        const float* __restrict__ u, const float* __restrict__ b1,
        float* __restrict__ h, int n4) {
    int i = blockIdx.x * 256 + threadIdx.x;
    if (i >= n4) return;
    float4 v = ((const float4*)u)[i];
    float4 bb = ((const float4*)b1)[i & 31];
    v.x = fmaxf(v.x + bb.x, 0.0f);
    v.y = fmaxf(v.y + bb.y, 0.0f);
    v.z = fmaxf(v.z + bb.z, 0.0f);
    v.w = fmaxf(v.w + bb.w, 0.0f);
    ((float4*)h)[i] = v;
}

// GEMM2: h[N,128] @ Wc2[128,8] -> out(+b2) cols 0,1; s2 cols 2,3; w2 cols 4,5
__global__ __launch_bounds__(256) void k_gemm2(
        const float* __restrict__ h, const float* __restrict__ Wc2,
        const float* __restrict__ b2, float* __restrict__ out,
        float* __restrict__ s2, float* __restrict__ w2, int N) {
    __shared__ float Ws[128 * 8];
    int tid = threadIdx.x;
    for (int idx = tid; idx < 128 * 8; idx += 256) Ws[idx] = Wc2[idx];
    __syncthreads();

    int rl = tid >> 3;
    int sub = tid & 7;
    int row = blockIdx.x * 32 + rl;
    if (row >= N) return;

    float4 accA = {0, 0, 0, 0};
    float4 accB = {0, 0, 0, 0};
    const float4* hp = (const float4*)(h + (size_t)row * NH + sub * 16);
#pragma unroll
    for (int q = 0; q < 4; ++q) {
        float4 hv = hp[q];
        float he[4] = {hv.x, hv.y, hv.z, hv.w};
#pragma unroll
        for (int t = 0; t < 4; ++t) {
            int k = sub * 16 + q * 4 + t;
            float4 wa = *(const float4*)&Ws[k * 8 + 0];
            float4 wb = *(const float4*)&Ws[k * 8 + 4];
            accA.x += he[t] * wa.x; accA.y += he[t] * wa.y;
            accA.z += he[t] * wa.z; accA.w += he[t] * wa.w;
            accB.x += he[t] * wb.x; accB.y += he[t] * wb.y;
        }
    }
#pragma unroll
    for (int off = 4; off; off >>= 1) {
        accA.x += __shfl_xor(accA.x, off);
        accA.y += __shfl_xor(accA.y, off);
        accA.z += __shfl_xor(accA.z, off);
        accA.w += __shfl_xor(accA.w, off);
        accB.x += __shfl_xor(accB.x, off);
        accB.y += __shfl_xor(accB.y, off);
    }
    if (sub == 0) {
        out[(size_t)row * 2 + 0] = accA.x + b2[0];
        out[(size_t)row * 2 + 1] = accA.y + b2[1];
        s2[(size_t)row * 2 + 0] = accA.z;
        s2[(size_t)row * 2 + 1] = accA.w;
        w2[(size_t)row * 2 + 0] = accB.x;
        w2[(size_t)row * 2 + 1] = accB.y;
    }
}

// prop on 2-wide features: one thread per edge
__global__ __launch_bounds__(256) void k_prop2(
        const int* __restrict__ erow, const int* __restrict__ ecol,
        const float* __restrict__ nrm, const float* __restrict__ src,
        float* __restrict__ dst, float scale, int E) {
    int e = blockIdx.x * 256 + threadIdx.x;
    if (e >= E) return;
    int r = erow[e];
    int c = ecol[e];
    float nv = nrm[e] * scale;
    float2 v = *(const float2*)(src + (size_t)c * 2);
    atomAddF(dst + (size_t)r * 2 + 0, nv * v.x);
    atomAddF(dst + (size_t)r * 2 + 1, nv * v.y);
}

extern "C" void kernel_launch(void* const* d_in, const int* in_sizes, int n_in,
                              void* d_out, int out_size, void* d_ws, size_t ws_size,
                              hipStream_t stream) {
    const float* x   = (const float*)d_in[0];
    const int* eidx  = (const int*)d_in[1];   // harness converts int64 -> int32
    const float* W1  = (const float*)d_in[2];
    const float* b1  = (const float*)d_in[3];
    const float* W2  = (const float*)d_in[4];
    const float* b2  = (const float*)d_in[5];
    float* out       = (float*)d_out;

    int N = in_sizes[0] / NF;
    int E = in_sizes[1] / 2;
    const int* erow = eidx;
    const int* ecol = eidx + E;

    char* p = (char*)d_ws;
    auto alloc = [&](size_t bytes) {
        char* q = p;
        p += (bytes + 255) & ~(size_t)255;
        return q;
    };
    float* u   = (float*)alloc((size_t)N * NH * 4);
    float* s   = (float*)alloc((size_t)N * NH * 4);
    float* w   = (float*)alloc((size_t)N * NH * 4);   // later reused as h
    float* dis = (float*)alloc((size_t)N * 4);
    float* nrm = (float*)alloc((size_t)E * 4);
    float* Wc1 = (float*)alloc((size_t)NF * NCOLS * 4);
    float* Wc2 = (float*)alloc((size_t)128 * 8 * 4);
    float* s2  = (float*)alloc((size_t)N * 2 * 4);
    float* w2  = (float*)alloc((size_t)N * 2 * 4);

    hipMemsetAsync(dis, 0, (size_t)N * 4, stream);

    int gE = (E + 255) / 256;
    int gN = (N + 255) / 256;

    k_deg<<<gE, 256, 0, stream>>>(erow, dis, E);
    k_dis<<<gN, 256, 0, stream>>>(dis, N);
    k_norm<<<gE, 256, 0, stream>>>(erow, ecol, dis, nrm, E);
    k_wc1<<<(NF * NCOLS + 255) / 256, 256, 0, stream>>>(W1, Wc1);
    k_wc2<<<4, 256, 0, stream>>>(W2, Wc2);

    dim3 g1((N + 63) / 64, NCOLS / 64);
    k_gemm1<<<g1, 256, 0, stream>>>(x, Wc1, u, s, w, N);

    int gP = (int)(((size_t)E * 32 + 255) / 256);
    // s += 2 * prop(w)
    k_prop128<<<gP, 256, 0, stream>>>(erow, ecol, nrm, w, s, 2.0f, E);
    // u += prop(s)
    k_prop128<<<gP, 256, 0, stream>>>(erow, ecol, nrm, s, u, 1.0f, E);

    int n4 = N * NH / 4;
    k_relu_bias<<<(n4 + 255) / 256, 256, 0, stream>>>(u, b1, w, n4);

    k_gemm2<<<(N + 31) / 32, 256, 0, stream>>>(w, Wc2, b2, out, s2, w2, N);

    // s2 += 2 * prop(w2); out += prop(s2)
    k_prop2<<<gE, 256, 0, stream>>>(erow, ecol, nrm, w2, s2, 2.0f, E);
    k_prop2<<<gE, 256, 0, stream>>>(erow, ecol, nrm, s2, out, 1.0f, E);
}

// Round 3
// 1896.084 us; speedup vs baseline: 6.4208x; 6.4208x over previous
//
#include <hip/hip_runtime.h>
#include <hip/hip_bf16.h>
#include <stdint.h>

#define NF 165
#define NH 128
#define NCOLS 384
#define KT 15
#define NKT 11

__device__ __forceinline__ void atomAddF(float* p, float v) {
    __hip_atomic_fetch_add(p, v, __ATOMIC_RELAXED, __HIP_MEMORY_SCOPE_AGENT);
}

// ---- CSR build ----------------------------------------------------------

// Count degree per destination row (int atomics).
__global__ __launch_bounds__(256) void k_count(
        const int* __restrict__ erow, int* __restrict__ cnt, int E) {
    int e = blockIdx.x * 256 + threadIdx.x;
    if (e >= E) return;
    atomicAdd(&cnt[erow[e]], 1);
}

// dis[i] = cnt>0 ? rsqrt(cnt) : 0
__global__ __launch_bounds__(256) void k_dis(
        const int* __restrict__ cnt, float* __restrict__ dis, int N) {
    int i = blockIdx.x * 256 + threadIdx.x;
    if (i >= N) return;
    int d = cnt[i];
    dis[i] = (d > 0) ? rsqrtf((float)d) : 0.0f;
}

// Exclusive scan, stage 1: blocks of 1024 (256 thr x 4 elems).
__global__ __launch_bounds__(256) void k_scan1(
        const int* __restrict__ cnt, int* __restrict__ off,
        int* __restrict__ bsum, int N) {
    __shared__ int sh[256];
    int t = threadIdx.x;
    int base = blockIdx.x * 1024 + t * 4;
    int v0 = (base + 0 < N) ? cnt[base + 0] : 0;
    int v1 = (base + 1 < N) ? cnt[base + 1] : 0;
    int v2 = (base + 2 < N) ? cnt[base + 2] : 0;
    int v3 = (base + 3 < N) ? cnt[base + 3] : 0;
    int tsum = v0 + v1 + v2 + v3;
    sh[t] = tsum;
    __syncthreads();
#pragma unroll
    for (int ofs = 1; ofs < 256; ofs <<= 1) {
        int x = (t >= ofs) ? sh[t - ofs] : 0;
        __syncthreads();
        sh[t] += x;
        __syncthreads();
    }
    int excl = sh[t] - tsum;
    if (t == 255) bsum[blockIdx.x] = sh[t];
    if (base + 0 < N) off[base + 0] = excl;
    excl += v0;
    if (base + 1 < N) off[base + 1] = excl;
    excl += v1;
    if (base + 2 < N) off[base + 2] = excl;
    excl += v2;
    if (base + 3 < N) off[base + 3] = excl;
}

// Stage 2: exclusive scan of block sums (NB <= 256) in one block.
__global__ __launch_bounds__(256) void k_scan2(int* __restrict__ bsum, int NB) {
    __shared__ int sh[256];
    int t = threadIdx.x;
    int v = (t < NB) ? bsum[t] : 0;
    sh[t] = v;
    __syncthreads();
#pragma unroll
    for (int ofs = 1; ofs < 256; ofs <<= 1) {
        int x = (t >= ofs) ? sh[t - ofs] : 0;
        __syncthreads();
        sh[t] += x;
        __syncthreads();
    }
    if (t < NB) bsum[t] = sh[t] - v;
}

// Stage 3: add block offsets; mirror into cursor; set off[N]=E.
__global__ __launch_bounds__(256) void k_scan3(
        int* __restrict__ off, int* __restrict__ cur,
        const int* __restrict__ bsum, int N, int E) {
    int i = blockIdx.x * 256 + threadIdx.x;
    if (i >= N) return;
    int v = off[i] + bsum[i >> 10];
    off[i] = v;
    cur[i] = v;
    if (i == 0) off[N] = E;
}

// Scatter edges into row-sorted order; fuse norm computation.
__global__ __launch_bounds__(256) void k_scatter(
        const int* __restrict__ erow, const int* __restrict__ ecol,
        const float* __restrict__ dis, int* __restrict__ cur,
        int* __restrict__ scol, float* __restrict__ snrm, int E) {
    int e = blockIdx.x * 256 + threadIdx.x;
    if (e >= E) return;
    int r = erow[e];
    int c = ecol[e];
    int pos = atomicAdd(&cur[r], 1);
    scol[pos] = c;
    snrm[pos] = -dis[r] * dis[c];
}

// ---- weights ------------------------------------------------------------

// Wc1[165][384]: cols 0..127 = W1[0]-W1[2]; 128..255 = W1[1]; 256..383 = W1[2]
__global__ __launch_bounds__(256) void k_wc1(const float* __restrict__ W1,
                                             float* __restrict__ Wc1) {
    int gid = blockIdx.x * 256 + threadIdx.x;
    if (gid >= NF * NCOLS) return;
    int i = gid / NCOLS;
    int j = gid % NCOLS;
    float v;
    if (j < 128)      v = W1[i * 128 + j] - W1[2 * 21120 + i * 128 + j];
    else if (j < 256) v = W1[21120 + i * 128 + (j - 128)];
    else              v = W1[42240 + i * 128 + (j - 256)];
    Wc1[gid] = v;
}

// Wc2[128][8]: cols 0,1 = W2[0]-W2[2]; 2,3 = W2[1]; 4,5 = W2[2]; 6,7 = 0
__global__ __launch_bounds__(256) void k_wc2(const float* __restrict__ W2,
                                             float* __restrict__ Wc2) {
    int gid = blockIdx.x * 256 + threadIdx.x;
    if (gid >= 128 * 8) return;
    int k = gid >> 3;
    int c = gid & 7;
    float v = 0.0f;
    if (c < 2)      v = W2[k * 2 + c] - W2[512 + k * 2 + c];
    else if (c < 4) v = W2[256 + k * 2 + (c - 2)];
    else if (c < 6) v = W2[512 + k * 2 + (c - 4)];
    Wc2[gid] = v;
}

// ---- dense kernels ------------------------------------------------------

// GEMM1: x[N,165] @ Wc1[165,384] -> u | s | w  (64x64 tile, 4x4/thread)
__global__ __launch_bounds__(256) void k_gemm1(
        const float* __restrict__ x, const float* __restrict__ Wc,
        float* __restrict__ u, float* __restrict__ s, float* __restrict__ w, int N) {
    __shared__ float As[KT][64];
    __shared__ float Bs[KT][64];

    int row0 = blockIdx.x * 64;
    int col0 = blockIdx.y * 64;
    int tid = threadIdx.x;
    int tx = tid & 15, ty = tid >> 4;

    float acc[4][4] = {};

    for (int kt = 0; kt < NKT; ++kt) {
        int k0 = kt * KT;
        for (int idx = tid; idx < 64 * KT; idx += 256) {
            int r = idx & 63;
            int k = idx >> 6;
            int row = row0 + r;
            As[k][r] = (row < N) ? x[(size_t)row * NF + k0 + k] : 0.0f;
        }
        for (int idx = tid; idx < KT * 64; idx += 256) {
            int k = idx >> 6;
            int c = idx & 63;
            Bs[k][c] = Wc[(size_t)(k0 + k) * NCOLS + col0 + c];
        }
        __syncthreads();
#pragma unroll
        for (int kk = 0; kk < KT; ++kk) {
            float4 a = *(const float4*)&As[kk][ty * 4];
            float4 b = *(const float4*)&Bs[kk][tx * 4];
            float av[4] = {a.x, a.y, a.z, a.w};
            float bv[4] = {b.x, b.y, b.z, b.w};
#pragma unroll
            for (int i = 0; i < 4; ++i)
#pragma unroll
                for (int j = 0; j < 4; ++j)
                    acc[i][j] += av[i] * bv[j];
        }
        __syncthreads();
    }

    int cbase = col0 + tx * 4;
    int g = cbase >> 7;
    int cc = cbase & 127;
    float* dst = (g == 0) ? u : (g == 1) ? s : w;
#pragma unroll
    for (int i = 0; i < 4; ++i) {
        int row = row0 + ty * 4 + i;
        if (row < N) {
            float4 v = {acc[i][0], acc[i][1], acc[i][2], acc[i][3]};
            *(float4*)(dst + (size_t)row * NH + cc) = v;
        }
    }
}

// CSR prop, 128-wide: dst[r] = add[r] + scale * sum_e nrm[e]*src[col[e]]
// One wave (64 lanes) per row; lane handles float2 slice.
__global__ __launch_bounds__(256) void k_prop128_csr(
        const int* __restrict__ off, const int* __restrict__ scol,
        const float* __restrict__ snrm, const float* __restrict__ src,
        const float* __restrict__ add, float* __restrict__ dst,
        float scale, int N) {
    int wid = (blockIdx.x * 256 + threadIdx.x) >> 6;
    if (wid >= N) return;
    int lane = threadIdx.x & 63;
    int e0 = off[wid], e1 = off[wid + 1];
    float a0 = 0.0f, a1 = 0.0f;
    for (int e = e0; e < e1; ++e) {
        int c = scol[e];
        float nv = snrm[e];
        float2 v = *(const float2*)(src + (size_t)c * NH + lane * 2);
        a0 += nv * v.x;
        a1 += nv * v.y;
    }
    float2 ad = *(const float2*)(add + (size_t)wid * NH + lane * 2);
    float2 o = {ad.x + scale * a0, ad.y + scale * a1};
    *(float2*)(dst + (size_t)wid * NH + lane * 2) = o;
}

// h = relu(u + b1) (float4)
__global__ __launch_bounds__(256) void k_relu_bias(
        const float* __restrict__ u, const float* __restrict__ b1,
        float* __restrict__ h, int n4) {
    int i = blockIdx.x * 256 + threadIdx.x;
    if (i >= n4) return;
    float4 v = ((const float4*)u)[i];
    float4 bb = ((const float4*)b1)[i & 31];
    v.x = fmaxf(v.x + bb.x, 0.0f);
    v.y = fmaxf(v.y + bb.y, 0.0f);
    v.z = fmaxf(v.z + bb.z, 0.0f);
    v.w = fmaxf(v.w + bb.w, 0.0f);
    ((float4*)h)[i] = v;
}

// GEMM2: h[N,128] @ Wc2[128,8] -> out(+b2), s2, w2
__global__ __launch_bounds__(256) void k_gemm2(
        const float* __restrict__ h, const float* __restrict__ Wc2,
        const float* __restrict__ b2, float* __restrict__ out,
        float* __restrict__ s2, float* __restrict__ w2, int N) {
    __shared__ float Ws[128 * 8];
    int tid = threadIdx.x;
    for (int idx = tid; idx < 128 * 8; idx += 256) Ws[idx] = Wc2[idx];
    __syncthreads();

    int rl = tid >> 3;
    int sub = tid & 7;
    int row = blockIdx.x * 32 + rl;
    if (row >= N) return;

    float4 accA = {0, 0, 0, 0};
    float4 accB = {0, 0, 0, 0};
    const float4* hp = (const float4*)(h + (size_t)row * NH + sub * 16);
#pragma unroll
    for (int q = 0; q < 4; ++q) {
        float4 hv = hp[q];
        float he[4] = {hv.x, hv.y, hv.z, hv.w};
#pragma unroll
        for (int t = 0; t < 4; ++t) {
            int k = sub * 16 + q * 4 + t;
            float4 wa = *(const float4*)&Ws[k * 8 + 0];
            float4 wb = *(const float4*)&Ws[k * 8 + 4];
            accA.x += he[t] * wa.x; accA.y += he[t] * wa.y;
            accA.z += he[t] * wa.z; accA.w += he[t] * wa.w;
            accB.x += he[t] * wb.x; accB.y += he[t] * wb.y;
        }
    }
#pragma unroll
    for (int off = 4; off; off >>= 1) {
        accA.x += __shfl_xor(accA.x, off);
        accA.y += __shfl_xor(accA.y, off);
        accA.z += __shfl_xor(accA.z, off);
        accA.w += __shfl_xor(accA.w, off);
        accB.x += __shfl_xor(accB.x, off);
        accB.y += __shfl_xor(accB.y, off);
    }
    if (sub == 0) {
        out[(size_t)row * 2 + 0] = accA.x + b2[0];
        out[(size_t)row * 2 + 1] = accA.y + b2[1];
        s2[(size_t)row * 2 + 0] = accA.z;
        s2[(size_t)row * 2 + 1] = accA.w;
        w2[(size_t)row * 2 + 0] = accB.x;
        w2[(size_t)row * 2 + 1] = accB.y;
    }
}

// CSR prop, 2-wide: one thread per row.
__global__ __launch_bounds__(256) void k_prop2_csr(
        const int* __restrict__ off, const int* __restrict__ scol,
        const float* __restrict__ snrm, const float* __restrict__ src,
        const float* __restrict__ add, float* __restrict__ dst,
        float scale, int N) {
    int r = blockIdx.x * 256 + threadIdx.x;
    if (r >= N) return;
    int e0 = off[r], e1 = off[r + 1];
    float a0 = 0.0f, a1 = 0.0f;
    for (int e = e0; e < e1; ++e) {
        int c = scol[e];
        float nv = snrm[e];
        float2 v = *(const float2*)(src + (size_t)c * 2);
        a0 += nv * v.x;
        a1 += nv * v.y;
    }
    float2 ad = *(const float2*)(add + (size_t)r * 2);
    float2 o = {ad.x + scale * a0, ad.y + scale * a1};
    *(float2*)(dst + (size_t)r * 2) = o;
}

extern "C" void kernel_launch(void* const* d_in, const int* in_sizes, int n_in,
                              void* d_out, int out_size, void* d_ws, size_t ws_size,
                              hipStream_t stream) {
    const float* x   = (const float*)d_in[0];
    const int* eidx  = (const int*)d_in[1];   // harness converts int64 -> int32
    const float* W1  = (const float*)d_in[2];
    const float* b1  = (const float*)d_in[3];
    const float* W2  = (const float*)d_in[4];
    const float* b2  = (const float*)d_in[5];
    float* out       = (float*)d_out;

    int N = in_sizes[0] / NF;
    int E = in_sizes[1] / 2;
    const int* erow = eidx;
    const int* ecol = eidx + E;

    char* p = (char*)d_ws;
    auto alloc = [&](size_t bytes) {
        char* q = p;
        p += (bytes + 255) & ~(size_t)255;
        return q;
    };
    float* u    = (float*)alloc((size_t)N * NH * 4);
    float* s    = (float*)alloc((size_t)N * NH * 4);
    float* w    = (float*)alloc((size_t)N * NH * 4);   // later reused as h
    float* dis  = (float*)alloc((size_t)N * 4);
    int* cnt    = (int*)alloc((size_t)N * 4);
    int* off    = (int*)alloc((size_t)(N + 1) * 4);
    int* cur    = (int*)alloc((size_t)N * 4);
    int* bsum   = (int*)alloc((size_t)256 * 4);
    int* scol   = (int*)alloc((size_t)E * 4);
    float* snrm = (float*)alloc((size_t)E * 4);
    float* Wc1  = (float*)alloc((size_t)NF * NCOLS * 4);
    float* Wc2  = (float*)alloc((size_t)128 * 8 * 4);
    float* s2   = (float*)alloc((size_t)N * 2 * 4);
    float* w2   = (float*)alloc((size_t)N * 2 * 4);

    hipMemsetAsync(cnt, 0, (size_t)N * 4, stream);

    int gE = (E + 255) / 256;
    int gN = (N + 255) / 256;
    int NB = (N + 1023) / 1024;   // 196 <= 256

    // CSR build
    k_count<<<gE, 256, 0, stream>>>(erow, cnt, E);
    k_dis<<<gN, 256, 0, stream>>>(cnt, dis, N);
    k_scan1<<<NB, 256, 0, stream>>>(cnt, off, bsum, N);
    k_scan2<<<1, 256, 0, stream>>>(bsum, NB);
    k_scan3<<<gN, 256, 0, stream>>>(off, cur, bsum, N, E);
    k_scatter<<<gE, 256, 0, stream>>>(erow, ecol, dis, cur, scol, snrm, E);

    // weights
    k_wc1<<<(NF * NCOLS + 255) / 256, 256, 0, stream>>>(W1, Wc1);
    k_wc2<<<4, 256, 0, stream>>>(W2, Wc2);

    // layer 1
    dim3 g1((N + 63) / 64, NCOLS / 64);
    k_gemm1<<<g1, 256, 0, stream>>>(x, Wc1, u, s, w, N);

    int gW = (N * 64 + 255) / 256;   // one wave per row
    // s = s + 2*prop(w)
    k_prop128_csr<<<gW, 256, 0, stream>>>(off, scol, snrm, w, s, s, 2.0f, N);
    // u = u + prop(s)
    k_prop128_csr<<<gW, 256, 0, stream>>>(off, scol, snrm, s, u, u, 1.0f, N);

    int n4 = N * NH / 4;
    k_relu_bias<<<(n4 + 255) / 256, 256, 0, stream>>>(u, b1, w, n4);

    // layer 2
    k_gemm2<<<(N + 31) / 32, 256, 0, stream>>>(w, Wc2, b2, out, s2, w2, N);
    // s2 = s2 + 2*prop(w2)
    k_prop2_csr<<<gN, 256, 0, stream>>>(off, scol, snrm, w2, s2, s2, 2.0f, N);
    // out = out + prop(s2)
    k_prop2_csr<<<gN, 256, 0, stream>>>(off, scol, snrm, s2, out, out, 1.0f, N);
}